// Round 1
// baseline (2743.629 us; speedup 1.0000x reference)
//
#include <hip/hip_runtime.h>
#include <hip/hip_bf16.h>

typedef short short8 __attribute__((ext_vector_type(8)));
typedef float f32x4 __attribute__((ext_vector_type(4)));

// ---- workspace layout (bytes) ----
#define OFF_U   0x0UL        // U bf16 [1024][1024]        2 MiB
#define OFF_W   0x200000UL   // W bf16 [1024][512]         1 MiB
#define OFF_PRE 0x300000UL   // pre bf16 [t=512][b=128][i=1024]  128 MiB
#define OFF_H0  0x8300000UL  // h buf0 bf16 [128][1024]    256 KiB
#define OFF_H1  0x8340000UL  // h buf1 bf16 [128][1024]    256 KiB
#define OFF_CNT 0x8380000UL  // flags uint [8][512]        16 KiB

static __device__ __forceinline__ unsigned short f2bf(float f) {
  return __builtin_bit_cast(unsigned short, __float2bfloat16(f));
}
static __device__ __forceinline__ float bf2f(unsigned short u) {
  unsigned int v = (unsigned int)u << 16;
  return __builtin_bit_cast(float, v);
}
static __device__ __forceinline__ unsigned int pack2(float a, float b) {
  return (unsigned int)f2bf(a) | ((unsigned int)f2bf(b) << 16);
}

// ---------------- fp32 -> bf16 bulk convert ----------------
__global__ __launch_bounds__(256) void cvt_bf16(const float* __restrict__ in,
                                                unsigned short* __restrict__ out, int n4) {
  int idx = blockIdx.x * 256 + threadIdx.x;
  if (idx < n4) {
    float4 v = *(const float4*)&in[idx * 4];
    uint2 p; p.x = pack2(v.x, v.y); p.y = pack2(v.z, v.w);
    *(uint2*)&out[idx * 4] = p;
  }
}

// ---------------- pre = gather(emb,x) @ W^T   (stored [t][b][i], bf16, NO bias) --------
// M-tile = one t (128 b rows), N-tile = 128 i cols, K = 512.
__global__ __launch_bounds__(256) void pre_gemm(const int* __restrict__ x,
                                                const float* __restrict__ emb,
                                                const unsigned short* __restrict__ Wbf,
                                                unsigned short* __restrict__ pre) {
  const int t   = blockIdx.y;           // 0..511
  const int n0  = blockIdx.x * 128;     // i offset
  const int tid = threadIdx.x;
  const int lane = tid & 63, w = tid >> 6;
  const int q = lane >> 4, l15 = lane & 15;

  __shared__ unsigned short Alds[128][72];  // +8 pad
  __shared__ unsigned short Blds[128][72];
  __shared__ int tok[128];
  if (tid < 128) tok[tid] = x[tid * 512 + t];   // x[b][t]
  __syncthreads();

  f32x4 acc[4][4];
  #pragma unroll
  for (int a = 0; a < 4; ++a)
    #pragma unroll
    for (int b = 0; b < 4; ++b) acc[a][b] = {0.f, 0.f, 0.f, 0.f};

  const int wm = (w & 1) * 64, wn = (w >> 1) * 64;

  for (int k0 = 0; k0 < 512; k0 += 64) {
    // stage A: 128 rows x 64 cols, fp32 gather -> bf16
    #pragma unroll
    for (int it = 0; it < 8; ++it) {
      int idx = it * 256 + tid;          // 0..2047 float4-chunks
      int r = idx >> 4, c4 = (idx & 15) * 4;
      float4 v = *(const float4*)&emb[tok[r] * 512 + k0 + c4];
      uint2 p; p.x = pack2(v.x, v.y); p.y = pack2(v.z, v.w);
      *(uint2*)&Alds[r][c4] = p;
    }
    // stage B: 128 rows x 64 cols bf16 copy
    #pragma unroll
    for (int it = 0; it < 4; ++it) {
      int idx = it * 256 + tid;          // 0..1023 int4-chunks
      int r = idx >> 3, c8 = (idx & 7) * 8;
      *(int4*)&Blds[r][c8] = *(const int4*)&Wbf[(n0 + r) * 512 + k0 + c8];
    }
    __syncthreads();
    #pragma unroll
    for (int kt = 0; kt < 2; ++kt) {
      short8 af[4], bfr[4];
      #pragma unroll
      for (int mt = 0; mt < 4; ++mt) af[mt]  = *(const short8*)&Alds[wm + mt*16 + l15][kt*32 + q*8];
      #pragma unroll
      for (int nt = 0; nt < 4; ++nt) bfr[nt] = *(const short8*)&Blds[wn + nt*16 + l15][kt*32 + q*8];
      #pragma unroll
      for (int mt = 0; mt < 4; ++mt)
        #pragma unroll
        for (int nt = 0; nt < 4; ++nt)
          acc[mt][nt] = __builtin_amdgcn_mfma_f32_16x16x32_bf16(af[mt], bfr[nt], acc[mt][nt], 0, 0, 0);
    }
    __syncthreads();
  }
  // epilogue: C row = b (within tile), col = i. C mapping: col=lane&15, row=4*(lane>>4)+reg
  #pragma unroll
  for (int mt = 0; mt < 4; ++mt) {
    int brow = wm + mt * 16 + q * 4;
    #pragma unroll
    for (int nt = 0; nt < 4; ++nt) {
      int i = n0 + wn + nt * 16 + l15;
      #pragma unroll
      for (int r = 0; r < 4; ++r)
        pre[(t * 128 + brow + r) * 1024 + i] = f2bf(acc[mt][nt][r]);
    }
  }
}

// ---------------- persistent recurrence ----------------
// 64 wgs = 8 clusters (16 batch each) x 8 i-slices (128 rows each).
// wg = 8 waves = 4 m-groups (32 rows) x 2 K-halves (512). U slice lives in VGPRs.
__global__ __launch_bounds__(512, 2) void recurrence(const unsigned short* __restrict__ Ubf,
                                                     const unsigned short* __restrict__ pre,
                                                     const float* __restrict__ Wb,
                                                     const float* __restrict__ Ub,
                                                     unsigned short* __restrict__ h0buf,
                                                     unsigned short* __restrict__ h1buf,
                                                     unsigned int* __restrict__ cnt) {
  const int c   = blockIdx.x & 7;        // cluster (XCD-affine under round-robin)
  const int s   = blockIdx.x >> 3;       // i-slice
  const int tid = threadIdx.x;
  const int lane = tid & 63, w = tid >> 6;
  const int mg = w & 3, kh = w >> 2;
  const int q = lane >> 4, l15 = lane & 15;
  const int ibase = s * 128 + mg * 32;
  const int kbase = kh * 512;
  const int bglob = c * 16;

  __shared__ unsigned short hlds[16][1032];   // [b][k], +8 pad
  __shared__ float red[4][32][17];            // K-half partial C exchange

  // U A-fragments: 2 m-tiles x 16 k-tiles, resident for all 512 steps (128 VGPRs)
  short8 A[2][16];
  #pragma unroll
  for (int mt = 0; mt < 2; ++mt) {
    const unsigned short* Up = Ubf + (ibase + mt * 16 + l15) * 1024 + kbase + q * 8;
    #pragma unroll
    for (int kt = 0; kt < 16; ++kt) A[mt][kt] = *(const short8*)(Up + kt * 32);
  }
  // bias per (mt, q, reg): Wb + Ub folded here (pre has no bias)
  float4 bias0, bias1;
  {
    int i0 = ibase + q * 4;
    float4 wv = *(const float4*)&Wb[i0]; float4 uv = *(const float4*)&Ub[i0];
    bias0 = make_float4(wv.x + uv.x, wv.y + uv.y, wv.z + uv.z, wv.w + uv.w);
    i0 += 16;
    wv = *(const float4*)&Wb[i0]; uv = *(const float4*)&Ub[i0];
    bias1 = make_float4(wv.x + uv.x, wv.y + uv.y, wv.z + uv.z, wv.w + uv.w);
  }

  unsigned int* mycnt = cnt + c * 512;

  #pragma unroll 1
  for (int t = 0; t < 512; ++t) {
    if (t > 0) {
      if (tid == 0) {
        while (__hip_atomic_load(&mycnt[t - 1], __ATOMIC_ACQUIRE, __HIP_MEMORY_SCOPE_AGENT) < 8u)
          __builtin_amdgcn_s_sleep(1);
      }
      __syncthreads();
    }
    const unsigned short* hprev = (t & 1) ? h1buf : h0buf;
    // stage h[16 b][1024] -> LDS (32 KB, 4 x int4 per thread)
    #pragma unroll
    for (int it = 0; it < 4; ++it) {
      int idx = it * 512 + tid;                 // 16B chunk id
      int b = idx >> 7, k = (idx & 127) * 8;
      *(int4*)&hlds[b][k] = *(const int4*)&hprev[(bglob + b) * 1024 + k];
    }
    __syncthreads();

    f32x4 acc0 = {0.f, 0.f, 0.f, 0.f}, acc1 = {0.f, 0.f, 0.f, 0.f};
    #pragma unroll
    for (int kt = 0; kt < 16; ++kt) {
      short8 bfr = *(const short8*)&hlds[l15][kbase + kt * 32 + q * 8];
      acc0 = __builtin_amdgcn_mfma_f32_16x16x32_bf16(A[0][kt], bfr, acc0, 0, 0, 0);
      acc1 = __builtin_amdgcn_mfma_f32_16x16x32_bf16(A[1][kt], bfr, acc1, 0, 0, 0);
    }
    if (kh == 1) {
      #pragma unroll
      for (int r = 0; r < 4; ++r) {
        red[mg][q * 4 + r][l15]      = acc0[r];
        red[mg][16 + q * 4 + r][l15] = acc1[r];
      }
    }
    __syncthreads();
    if (kh == 0) {
      f32x4 s0, s1;
      #pragma unroll
      for (int r = 0; r < 4; ++r) {
        s0[r] = acc0[r] + red[mg][q * 4 + r][l15];
        s1[r] = acc1[r] + red[mg][16 + q * 4 + r][l15];
      }
      const int b = bglob + l15;
      unsigned short* hnew = ((t & 1) ? h0buf : h1buf) + b * 1024;
      const unsigned short* pr = pre + (t * 128 + b) * 1024;
      {
        int i0 = ibase + q * 4;
        ushort4 pv = *(const ushort4*)&pr[i0];
        float r0 = tanhf(s0[0] + bf2f(pv.x) + bias0.x);
        float r1 = tanhf(s0[1] + bf2f(pv.y) + bias0.y);
        float r2 = tanhf(s0[2] + bf2f(pv.z) + bias0.z);
        float r3 = tanhf(s0[3] + bf2f(pv.w) + bias0.w);
        uint2 pk; pk.x = pack2(r0, r1); pk.y = pack2(r2, r3);
        *(uint2*)&hnew[i0] = pk;
      }
      {
        int i0 = ibase + 16 + q * 4;
        ushort4 pv = *(const ushort4*)&pr[i0];
        float r0 = tanhf(s1[0] + bf2f(pv.x) + bias1.x);
        float r1 = tanhf(s1[1] + bf2f(pv.y) + bias1.y);
        float r2 = tanhf(s1[2] + bf2f(pv.z) + bias1.z);
        float r3 = tanhf(s1[3] + bf2f(pv.w) + bias1.w);
        uint2 pk; pk.x = pack2(r0, r1); pk.y = pack2(r2, r3);
        *(uint2*)&hnew[i0] = pk;
      }
    }
    __syncthreads();  // drains vmcnt: all waves' h stores at L2 before release
    if (tid == 0)
      __hip_atomic_fetch_add(&mycnt[t], 1u, __ATOMIC_RELEASE, __HIP_MEMORY_SCOPE_AGENT);
  }
}

// ---------------- final: sigmoid(h_T @ V^T + Vb) ----------------
__global__ __launch_bounds__(64) void final_out(const unsigned short* __restrict__ hT,
                                                const float* __restrict__ Vw,
                                                const float* __restrict__ Vb,
                                                float* __restrict__ out) {
  int b = blockIdx.x, lane = threadIdx.x;
  float sum = 0.f;
  #pragma unroll
  for (int k = 0; k < 16; ++k) {
    int i = k * 64 + lane;
    sum += bf2f(hT[b * 1024 + i]) * Vw[i];
  }
  #pragma unroll
  for (int off = 32; off; off >>= 1) sum += __shfl_down(sum, off);
  if (lane == 0) out[b] = 1.f / (1.f + expf(-(sum + Vb[0])));
}

extern "C" void kernel_launch(void* const* d_in, const int* in_sizes, int n_in,
                              void* d_out, int out_size, void* d_ws, size_t ws_size,
                              hipStream_t stream) {
  const int*   x   = (const int*)d_in[0];
  const float* emb = (const float*)d_in[1];
  const float* W_w = (const float*)d_in[2];
  const float* W_b = (const float*)d_in[3];
  const float* U_w = (const float*)d_in[4];
  const float* U_b = (const float*)d_in[5];
  const float* V_w = (const float*)d_in[6];
  const float* V_b = (const float*)d_in[7];
  float* out = (float*)d_out;
  char*  ws  = (char*)d_ws;

  unsigned short* Ubf = (unsigned short*)(ws + OFF_U);
  unsigned short* Wbf = (unsigned short*)(ws + OFF_W);
  unsigned short* pre = (unsigned short*)(ws + OFF_PRE);
  unsigned short* h0  = (unsigned short*)(ws + OFF_H0);
  unsigned short* h1  = (unsigned short*)(ws + OFF_H1);
  unsigned int*   cnt = (unsigned int*)(ws + OFF_CNT);

  // zero h0 (initial hidden state) + flags
  hipMemsetAsync(ws + OFF_H0, 0, (OFF_CNT - OFF_H0) + 0x4000, stream);

  cvt_bf16<<<1024, 256, 0, stream>>>(U_w, Ubf, 1024 * 1024 / 4);
  cvt_bf16<<<512, 256, 0, stream>>>(W_w, Wbf, 1024 * 512 / 4);

  pre_gemm<<<dim3(8, 512), 256, 0, stream>>>(x, emb, Wbf, pre);

  void* args[] = {&Ubf, &pre, &W_b, &U_b, &h0, &h1, &cnt};
  hipLaunchCooperativeKernel((void*)recurrence, dim3(64), dim3(512), args, 0, stream);

  final_out<<<128, 64, 0, stream>>>(h0, V_w, V_b, out);
}